// Round 1
// baseline (995.621 us; speedup 1.0000x reference)
//
#include <hip/hip_runtime.h>
#include <math.h>

#define NN 100000
#define NE 1600000
#define EPS_BN 1e-5f

// ---------------- edge dtype detection (int64 vs int32) ----------------
// If edges are int64 (little-endian), every odd int32 slot in the first rows
// is a high word == 0 (values < 100000). If int32, those slots are random
// indices and OR to nonzero with overwhelming probability.
__global__ void detect_kernel(const int* __restrict__ ei32, int* __restrict__ flag) {
  if (threadIdx.x == 0 && blockIdx.x == 0) {
    int acc = 0;
    for (int i = 0; i < 1024; ++i) acc |= ei32[2 * i + 1];
    *flag = (acc == 0) ? 1 : 0;
  }
}

__device__ __forceinline__ int edge_at(const void* ei, long long idx, int is64) {
  if (is64) return (int)((const long long*)ei)[idx];
  return ((const int*)ei)[idx];
}

// ---------------- degree count ----------------
__global__ void deg_kernel(const void* __restrict__ ei, const int* __restrict__ flag,
                           int* __restrict__ cnt) {
  int is64 = *flag;
  for (int e = blockIdx.x * blockDim.x + threadIdx.x; e < NE; e += gridDim.x * blockDim.x) {
    int d = edge_at(ei, (long long)NE + e, is64);
    atomicAdd(&cnt[d], 1);
  }
}

// ---------------- single-block exclusive scan + dis = rsqrt(deg+1) ----------------
__global__ __launch_bounds__(1024) void scan_kernel(const int* __restrict__ cnt,
                                                    int* __restrict__ row_start,
                                                    float* __restrict__ dis) {
  __shared__ int part[1024];
  int t = threadIdx.x;
  const int CH = (NN + 1023) / 1024;
  int lo = t * CH, hi = min(lo + CH, NN);
  int s = 0;
  for (int i = lo; i < hi; ++i) s += cnt[i];
  part[t] = s;
  __syncthreads();
  for (int off = 1; off < 1024; off <<= 1) {
    int v = (t >= off) ? part[t - off] : 0;
    __syncthreads();
    part[t] += v;
    __syncthreads();
  }
  int run = part[t] - s;  // exclusive prefix at chunk start
  for (int i = lo; i < hi; ++i) {
    int c = cnt[i];
    row_start[i] = run;
    run += c;
    dis[i] = rsqrtf((float)(c + 1));  // deg includes self loop -> >= 1
  }
  if (t == 1023) row_start[NN] = run;
}

// ---------------- CSR scatter ----------------
__global__ void scatter_kernel(const void* __restrict__ ei, const int* __restrict__ flag,
                               const int* __restrict__ row_start, int* __restrict__ cursor,
                               const float* __restrict__ dis, int* __restrict__ csr_src,
                               float* __restrict__ csr_w) {
  int is64 = *flag;
  for (int e = blockIdx.x * blockDim.x + threadIdx.x; e < NE; e += gridDim.x * blockDim.x) {
    int s = edge_at(ei, e, is64);
    int d = edge_at(ei, (long long)NE + e, is64);
    int pos = row_start[d] + atomicAdd(&cursor[d], 1);
    csr_src[pos] = s;
    csr_w[pos] = dis[s];
  }
}

// ---------------- GEMM: h[N][64] = x[N][K] @ W[64][K]^T ----------------
// 64 rows per block, wave w handles rows w*16..w*16+15, lane = output col.
// W tile XOR-swizzled in LDS so per-lane float4 reads avoid same-bank columns.
template <int K>
__global__ __launch_bounds__(256) void gemm_kernel(const float* __restrict__ x,
                                                   const float* __restrict__ Wm,
                                                   float* __restrict__ h) {
  constexpr int KC = K / 4;
  __shared__ float4 ws4[64 * KC];
  __shared__ float4 xs4[64 * KC];
  int t = threadIdx.x;
  int row0 = blockIdx.x * 64;
  const float4* W4 = (const float4*)Wm;
  for (int idx = t; idx < 64 * KC; idx += 256) {
    int j = idx / KC, kc = idx % KC;
    ws4[j * KC + (kc ^ (j & 7))] = W4[idx];
  }
  const float4* x4 = (const float4*)x;
  for (int idx = t; idx < 64 * KC; idx += 256) {
    int r = idx / KC, kc = idx % KC;
    int row = row0 + r;
    float4 v = make_float4(0.f, 0.f, 0.f, 0.f);
    if (row < NN) v = x4[(size_t)row * KC + kc];
    xs4[r * KC + kc] = v;
  }
  __syncthreads();
  int j = t & 63, wv = t >> 6;
  float acc[16];
#pragma unroll
  for (int r = 0; r < 16; ++r) acc[r] = 0.f;
  for (int kc = 0; kc < KC; ++kc) {
    float4 w = ws4[j * KC + (kc ^ (j & 7))];
#pragma unroll
    for (int r = 0; r < 16; ++r) {
      float4 xv = xs4[(wv * 16 + r) * KC + kc];  // wave-uniform -> LDS broadcast
      acc[r] += w.x * xv.x + w.y * xv.y + w.z * xv.z + w.w * xv.w;
    }
  }
#pragma unroll
  for (int r = 0; r < 16; ++r) {
    int row = row0 + wv * 16 + r;
    if (row < NN) h[(size_t)row * 64 + j] = acc[r];
  }
}

// ---------------- CSR aggregation + fused BN stats ----------------
// One wave per node; lane = feature. agg[i] = dis[i]*(sum_e h[src]*dis[src] + h[i]*dis[i])
__global__ __launch_bounds__(256) void agg_kernel(const float* __restrict__ h,
                                                  const int* __restrict__ row_start,
                                                  const int* __restrict__ csr_src,
                                                  const float* __restrict__ csr_w,
                                                  const float* __restrict__ dis,
                                                  float* __restrict__ agg,
                                                  float* __restrict__ stats) {
  int t = threadIdx.x, lane = t & 63, wv = t >> 6;
  int gw = blockIdx.x * 4 + wv;
  int nw = gridDim.x * 4;
  float ssum = 0.f, ssq = 0.f;
  for (int i0 = gw; i0 < NN; i0 += nw) {
    int i = __builtin_amdgcn_readfirstlane(i0);  // force scalar CSR walk
    int beg = row_start[i], end = row_start[i + 1];
    float di = dis[i];
    float acc = h[(size_t)i * 64 + lane] * di;  // self loop
    for (int e = beg; e < end; ++e) {
      acc += h[(size_t)csr_src[e] * 64 + lane] * csr_w[e];
    }
    acc *= di;
    agg[(size_t)i * 64 + lane] = acc;
    ssum += acc;
    ssq += acc * acc;
  }
  __shared__ float red[2][4][64];
  red[0][wv][lane] = ssum;
  red[1][wv][lane] = ssq;
  __syncthreads();
  if (wv == 0) {
    float a = red[0][0][lane] + red[0][1][lane] + red[0][2][lane] + red[0][3][lane];
    float b = red[1][0][lane] + red[1][1][lane] + red[1][2][lane] + red[1][3][lane];
    atomicAdd(&stats[lane], a);
    atomicAdd(&stats[64 + lane], b);
  }
}

// ---------------- fold stats into per-feature scale/shift ----------------
// BN of (agg + b): bias cancels (mean subtraction), so b is never needed.
__global__ void bnp_kernel(const float* __restrict__ stats, const float* __restrict__ g,
                           const float* __restrict__ be, float* __restrict__ bnp) {
  int f = threadIdx.x;
  if (f < 64) {
    float m = stats[f] / (float)NN;
    float v = stats[64 + f] / (float)NN - m * m;
    float sc = g[f] * rsqrtf(fmaxf(v, 0.f) + EPS_BN);
    bnp[f] = sc;
    bnp[64 + f] = be[f] - m * sc;
  }
}

// ---------------- BN apply + ReLU + optional residual ----------------
template <bool RES>
__global__ __launch_bounds__(256) void apply_kernel(const float* __restrict__ agg,
                                                    const float* __restrict__ bnp,
                                                    const float* __restrict__ xres,
                                                    float* __restrict__ out) {
  __shared__ float sc[64], sh[64];
  int t = threadIdx.x;
  if (t < 64) {
    sc[t] = bnp[t];
    sh[t] = bnp[64 + t];
  }
  __syncthreads();
  const int total4 = NN * 16;  // N*64/4
  for (int i = blockIdx.x * blockDim.x + t; i < total4; i += gridDim.x * blockDim.x) {
    float4 a = ((const float4*)agg)[i];
    int f = (i * 4) & 63;
    float4 y;
    y.x = fmaxf(fmaf(a.x, sc[f], sh[f]), 0.f);
    y.y = fmaxf(fmaf(a.y, sc[f + 1], sh[f + 1]), 0.f);
    y.z = fmaxf(fmaf(a.z, sc[f + 2], sh[f + 2]), 0.f);
    y.w = fmaxf(fmaf(a.w, sc[f + 3], sh[f + 3]), 0.f);
    if (RES) {
      float4 xr = ((const float4*)xres)[i];
      y.x += xr.x;
      y.y += xr.y;
      y.z += xr.z;
      y.w += xr.w;
    }
    ((float4*)out)[i] = y;
  }
}

extern "C" void kernel_launch(void* const* d_in, const int* in_sizes, int n_in,
                              void* d_out, int out_size, void* d_ws, size_t ws_size,
                              hipStream_t stream) {
  const float* x0 = (const float*)d_in[0];
  const void* ei = d_in[1];
  const float* W0 = (const float*)d_in[2];
  const float* g0 = (const float*)d_in[4];
  const float* be0 = (const float*)d_in[5];
  const float* W1 = (const float*)d_in[6];
  const float* g1 = (const float*)d_in[8];
  const float* be1 = (const float*)d_in[9];
  const float* W2 = (const float*)d_in[10];
  const float* g2 = (const float*)d_in[12];
  const float* be2 = (const float*)d_in[13];
  float* out = (float*)d_out;

  char* p = (char*)d_ws;
  auto carve = [&](size_t bytes) {
    char* q = p;
    p += (bytes + 255) & ~(size_t)255;
    return (void*)q;
  };
  float* bufA = (float*)carve((size_t)NN * 64 * 4);
  float* bufB = (float*)carve((size_t)NN * 64 * 4);
  float* bufC = (float*)carve((size_t)NN * 64 * 4);
  int* row_start = (int*)carve((size_t)(NN + 1) * 4);
  int* cursor = (int*)carve((size_t)NN * 4);
  float* dis = (float*)carve((size_t)NN * 4);
  int* csr_src = (int*)carve((size_t)NE * 4);
  float* csr_w = (float*)carve((size_t)NE * 4);
  float* stats = (float*)carve(128 * 4);
  float* bnp = (float*)carve(128 * 4);
  int* flag = (int*)carve(256);

  // ---- graph preprocessing (once; reused by all 3 layers) ----
  detect_kernel<<<1, 64, 0, stream>>>((const int*)ei, flag);
  hipMemsetAsync(cursor, 0, (size_t)NN * 4, stream);
  deg_kernel<<<2048, 256, 0, stream>>>(ei, flag, cursor);
  scan_kernel<<<1, 1024, 0, stream>>>(cursor, row_start, dis);
  hipMemsetAsync(cursor, 0, (size_t)NN * 4, stream);
  scatter_kernel<<<2048, 256, 0, stream>>>(ei, flag, row_start, cursor, dis, csr_src, csr_w);

  const int gemm_blocks = (NN + 63) / 64;

  // ---- layer 0 (no residual: 128 -> 64) ----
  hipMemsetAsync(stats, 0, 128 * 4, stream);
  gemm_kernel<128><<<gemm_blocks, 256, 0, stream>>>(x0, W0, bufB);
  agg_kernel<<<2048, 256, 0, stream>>>(bufB, row_start, csr_src, csr_w, dis, bufC, stats);
  bnp_kernel<<<1, 64, 0, stream>>>(stats, g0, be0, bnp);
  apply_kernel<false><<<1024, 256, 0, stream>>>(bufC, bnp, nullptr, bufA);

  // ---- layer 1 (residual) ----
  hipMemsetAsync(stats, 0, 128 * 4, stream);
  gemm_kernel<64><<<gemm_blocks, 256, 0, stream>>>(bufA, W1, bufB);
  agg_kernel<<<2048, 256, 0, stream>>>(bufB, row_start, csr_src, csr_w, dis, bufC, stats);
  bnp_kernel<<<1, 64, 0, stream>>>(stats, g1, be1, bnp);
  apply_kernel<true><<<1024, 256, 0, stream>>>(bufC, bnp, bufA, out);

  // ---- layer 2 (residual) ----
  hipMemsetAsync(stats, 0, 128 * 4, stream);
  gemm_kernel<64><<<gemm_blocks, 256, 0, stream>>>(out, W2, bufB);
  agg_kernel<<<2048, 256, 0, stream>>>(bufB, row_start, csr_src, csr_w, dis, bufC, stats);
  bnp_kernel<<<1, 64, 0, stream>>>(stats, g2, be2, bnp);
  apply_kernel<true><<<1024, 256, 0, stream>>>(bufC, bnp, out, out);
}

// Round 4
// 640.852 us; speedup vs baseline: 1.5536x; 1.5536x over previous
//
#include <hip/hip_runtime.h>
#include <math.h>

#define NN 100000
#define NE 1600000
#define EPS_BN 1e-5f
#define SCAN_BLK 98  // ceil(NN / 1024)

// ---------------- edge dtype detection (int64 vs int32) ----------------
// If edges are int64 (little-endian), every odd int32 slot is a high word == 0
// (values < 100000). If int32, those slots are random indices -> OR nonzero.
__global__ void detect_kernel(const int* __restrict__ ei32, int* __restrict__ flag) {
  __shared__ int red[256];
  int t = threadIdx.x;
  int acc = 0;
#pragma unroll
  for (int k = 0; k < 4; ++k) acc |= ei32[2 * (t * 4 + k) + 1];
  red[t] = acc;
  __syncthreads();
  for (int off = 128; off > 0; off >>= 1) {
    if (t < off) red[t] |= red[t + off];
    __syncthreads();
  }
  if (t == 0) *flag = (red[0] == 0) ? 1 : 0;
}

__device__ __forceinline__ int edge_at(const void* ei, long long idx, int is64) {
  if (is64) return (int)((const long long*)ei)[idx];
  return ((const int*)ei)[idx];
}

// ---------------- degree count ----------------
__global__ void deg_kernel(const void* __restrict__ ei, const int* __restrict__ flag,
                           int* __restrict__ cnt) {
  int is64 = *flag;
  for (int e = blockIdx.x * blockDim.x + threadIdx.x; e < NE; e += gridDim.x * blockDim.x) {
    int d = edge_at(ei, (long long)NE + e, is64);
    atomicAdd(&cnt[d], 1);
  }
}

// ---------------- multi-block exclusive scan over cnt[NN] ----------------
// Phase A: per-block (1024-element) sums.
__global__ __launch_bounds__(256) void scanA_kernel(const int* __restrict__ cnt,
                                                    int* __restrict__ partial) {
  __shared__ int red[256];
  int t = threadIdx.x;
  int base = blockIdx.x * 256 + t;  // int4 index
  int s = 0;
  if (base * 4 < NN) {  // NN % 4 == 0 -> all-or-nothing per thread
    int4 v = ((const int4*)cnt)[base];
    s = v.x + v.y + v.z + v.w;
  }
  red[t] = s;
  __syncthreads();
  for (int off = 128; off > 0; off >>= 1) {
    if (t < off) red[t] += red[t + off];
    __syncthreads();
  }
  if (t == 0) partial[blockIdx.x] = red[0];
}

// Phase B: scan SCAN_BLK partials (1 block), write exclusive offsets + total.
__global__ __launch_bounds__(128) void scanB_kernel(const int* __restrict__ partial,
                                                    int* __restrict__ offs,
                                                    int* __restrict__ row_start) {
  __shared__ int sh[128];
  int t = threadIdx.x;
  int v = (t < SCAN_BLK) ? partial[t] : 0;
  sh[t] = v;
  __syncthreads();
  for (int off = 1; off < 128; off <<= 1) {
    int u = (t >= off) ? sh[t - off] : 0;
    __syncthreads();
    sh[t] += u;
    __syncthreads();
  }
  if (t < SCAN_BLK) offs[t] = sh[t] - v;  // exclusive
  if (t == 127) row_start[NN] = sh[127];  // total (== NE)
}

// Phase C: local exclusive scan + block offset -> row_start, dis.
__global__ __launch_bounds__(256) void scanC_kernel(const int* __restrict__ cnt,
                                                    const int* __restrict__ offs,
                                                    int* __restrict__ row_start,
                                                    float* __restrict__ dis) {
  __shared__ int sh[256];
  int t = threadIdx.x;
  int base = blockIdx.x * 256 + t;  // int4 index
  int4 v = make_int4(0, 0, 0, 0);
  bool ok = (base * 4 < NN);
  if (ok) v = ((const int4*)cnt)[base];
  int s = v.x + v.y + v.z + v.w;
  sh[t] = s;
  __syncthreads();
  for (int off = 1; off < 256; off <<= 1) {
    int u = (t >= off) ? sh[t - off] : 0;
    __syncthreads();
    sh[t] += u;
    __syncthreads();
  }
  if (ok) {
    int run = offs[blockIdx.x] + sh[t] - s;
    int i = base * 4;
    row_start[i] = run;
    dis[i] = rsqrtf((float)(v.x + 1));
    run += v.x;
    row_start[i + 1] = run;
    dis[i + 1] = rsqrtf((float)(v.y + 1));
    run += v.y;
    row_start[i + 2] = run;
    dis[i + 2] = rsqrtf((float)(v.z + 1));
    run += v.z;
    row_start[i + 3] = run;
    dis[i + 3] = rsqrtf((float)(v.w + 1));
  }
}

// ---------------- CSR scatter (packed src+weight) ----------------
__global__ void scatter_kernel(const void* __restrict__ ei, const int* __restrict__ flag,
                               const int* __restrict__ row_start, int* __restrict__ cursor,
                               const float* __restrict__ dis, int2* __restrict__ csr_pack) {
  int is64 = *flag;
  for (int e = blockIdx.x * blockDim.x + threadIdx.x; e < NE; e += gridDim.x * blockDim.x) {
    int s = edge_at(ei, e, is64);
    int d = edge_at(ei, (long long)NE + e, is64);
    int pos = row_start[d] + atomicAdd(&cursor[d], 1);
    csr_pack[pos] = make_int2(s, __float_as_int(dis[s]));
  }
}

// ---------------- GEMM: h[N][64] = x[N][K] @ W[64][K]^T ----------------
template <int K>
__global__ __launch_bounds__(256) void gemm_kernel(const float* __restrict__ x,
                                                   const float* __restrict__ Wm,
                                                   float* __restrict__ h) {
  constexpr int KC = K / 4;
  __shared__ float4 ws4[64 * KC];
  __shared__ float4 xs4[64 * KC];
  int t = threadIdx.x;
  int row0 = blockIdx.x * 64;
  const float4* W4 = (const float4*)Wm;
  for (int idx = t; idx < 64 * KC; idx += 256) {
    int j = idx / KC, kc = idx % KC;
    ws4[j * KC + (kc ^ (j & 7))] = W4[idx];
  }
  const float4* x4 = (const float4*)x;
  for (int idx = t; idx < 64 * KC; idx += 256) {
    int r = idx / KC, kc = idx % KC;
    int row = row0 + r;
    float4 v = make_float4(0.f, 0.f, 0.f, 0.f);
    if (row < NN) v = x4[(size_t)row * KC + kc];
    xs4[r * KC + kc] = v;
  }
  __syncthreads();
  int j = t & 63, wv = t >> 6;
  float acc[16];
#pragma unroll
  for (int r = 0; r < 16; ++r) acc[r] = 0.f;
  for (int kc = 0; kc < KC; ++kc) {
    float4 w = ws4[j * KC + (kc ^ (j & 7))];
#pragma unroll
    for (int r = 0; r < 16; ++r) {
      float4 xv = xs4[(wv * 16 + r) * KC + kc];  // wave-uniform -> LDS broadcast
      acc[r] += w.x * xv.x + w.y * xv.y + w.z * xv.z + w.w * xv.w;
    }
  }
#pragma unroll
  for (int r = 0; r < 16; ++r) {
    int row = row0 + wv * 16 + r;
    if (row < NN) h[(size_t)row * 64 + j] = acc[r];
  }
}

// ---------------- CSR aggregation + fused BN stats ----------------
__global__ __launch_bounds__(256) void agg_kernel(const float* __restrict__ h,
                                                  const int* __restrict__ row_start,
                                                  const int2* __restrict__ csr_pack,
                                                  const float* __restrict__ dis,
                                                  float* __restrict__ agg,
                                                  float* __restrict__ stats) {
  int t = threadIdx.x, lane = t & 63, wv = t >> 6;
  int gw = blockIdx.x * 4 + wv;
  int nw = gridDim.x * 4;
  float ssum = 0.f, ssq = 0.f;
  for (int i0 = gw; i0 < NN; i0 += nw) {
    int i = __builtin_amdgcn_readfirstlane(i0);  // force scalar CSR walk
    int beg = row_start[i], end = row_start[i + 1];
    float di = dis[i];
    float acc = h[(size_t)i * 64 + lane] * di;  // self loop
    int e = beg;
    for (; e + 1 < end; e += 2) {
      int2 a0 = csr_pack[e];
      int2 a1 = csr_pack[e + 1];
      float v0 = h[(size_t)a0.x * 64 + lane];
      float v1 = h[(size_t)a1.x * 64 + lane];
      acc += v0 * __int_as_float(a0.y) + v1 * __int_as_float(a1.y);
    }
    if (e < end) {
      int2 a0 = csr_pack[e];
      acc += h[(size_t)a0.x * 64 + lane] * __int_as_float(a0.y);
    }
    acc *= di;
    agg[(size_t)i * 64 + lane] = acc;
    ssum += acc;
    ssq += acc * acc;
  }
  __shared__ float red[2][4][64];
  red[0][wv][lane] = ssum;
  red[1][wv][lane] = ssq;
  __syncthreads();
  if (wv == 0) {
    float a = red[0][0][lane] + red[0][1][lane] + red[0][2][lane] + red[0][3][lane];
    float b = red[1][0][lane] + red[1][1][lane] + red[1][2][lane] + red[1][3][lane];
    atomicAdd(&stats[lane], a);
    atomicAdd(&stats[64 + lane], b);
  }
}

// ---------------- fold stats into per-feature scale/shift ----------------
// BN of (agg + b): bias cancels (mean subtraction), so b is never needed.
__global__ void bnp_kernel(const float* __restrict__ stats, const float* __restrict__ g,
                           const float* __restrict__ be, float* __restrict__ bnp) {
  int f = threadIdx.x;
  if (f < 64) {
    float m = stats[f] / (float)NN;
    float v = stats[64 + f] / (float)NN - m * m;
    float sc = g[f] * rsqrtf(fmaxf(v, 0.f) + EPS_BN);
    bnp[f] = sc;
    bnp[64 + f] = be[f] - m * sc;
  }
}

// ---------------- BN apply + ReLU + optional residual ----------------
template <bool RES>
__global__ __launch_bounds__(256) void apply_kernel(const float* __restrict__ agg,
                                                    const float* __restrict__ bnp,
                                                    const float* __restrict__ xres,
                                                    float* __restrict__ out) {
  __shared__ float sc[64], sh[64];
  int t = threadIdx.x;
  if (t < 64) {
    sc[t] = bnp[t];
    sh[t] = bnp[64 + t];
  }
  __syncthreads();
  const int total4 = NN * 16;  // N*64/4
  for (int i = blockIdx.x * blockDim.x + t; i < total4; i += gridDim.x * blockDim.x) {
    float4 a = ((const float4*)agg)[i];
    int f = (i * 4) & 63;
    float4 y;
    y.x = fmaxf(fmaf(a.x, sc[f], sh[f]), 0.f);
    y.y = fmaxf(fmaf(a.y, sc[f + 1], sh[f + 1]), 0.f);
    y.z = fmaxf(fmaf(a.z, sc[f + 2], sh[f + 2]), 0.f);
    y.w = fmaxf(fmaf(a.w, sc[f + 3], sh[f + 3]), 0.f);
    if (RES) {
      float4 xr = ((const float4*)xres)[i];
      y.x += xr.x;
      y.y += xr.y;
      y.z += xr.z;
      y.w += xr.w;
    }
    ((float4*)out)[i] = y;
  }
}

extern "C" void kernel_launch(void* const* d_in, const int* in_sizes, int n_in,
                              void* d_out, int out_size, void* d_ws, size_t ws_size,
                              hipStream_t stream) {
  const float* x0 = (const float*)d_in[0];
  const void* ei = d_in[1];
  const float* W0 = (const float*)d_in[2];
  const float* g0 = (const float*)d_in[4];
  const float* be0 = (const float*)d_in[5];
  const float* W1 = (const float*)d_in[6];
  const float* g1 = (const float*)d_in[8];
  const float* be1 = (const float*)d_in[9];
  const float* W2 = (const float*)d_in[10];
  const float* g2 = (const float*)d_in[12];
  const float* be2 = (const float*)d_in[13];
  float* out = (float*)d_out;

  char* p = (char*)d_ws;
  auto carve = [&](size_t bytes) {
    char* q = p;
    p += (bytes + 255) & ~(size_t)255;
    return (void*)q;
  };
  float* bufA = (float*)carve((size_t)NN * 64 * 4);
  float* bufB = (float*)carve((size_t)NN * 64 * 4);
  float* bufC = (float*)carve((size_t)NN * 64 * 4);
  int* row_start = (int*)carve((size_t)(NN + 1) * 4);
  int* cursor = (int*)carve((size_t)NN * 4);
  float* dis = (float*)carve((size_t)NN * 4);
  int2* csr_pack = (int2*)carve((size_t)NE * 8);
  int* partial = (int*)carve(SCAN_BLK * 4);
  int* offs = (int*)carve(SCAN_BLK * 4);
  float* stats = (float*)carve(128 * 4);
  float* bnp = (float*)carve(128 * 4);
  int* flag = (int*)carve(256);

  // ---- graph preprocessing (once; reused by all 3 layers) ----
  detect_kernel<<<1, 256, 0, stream>>>((const int*)ei, flag);
  hipMemsetAsync(cursor, 0, (size_t)NN * 4, stream);
  deg_kernel<<<2048, 256, 0, stream>>>(ei, flag, cursor);
  scanA_kernel<<<SCAN_BLK, 256, 0, stream>>>(cursor, partial);
  scanB_kernel<<<1, 128, 0, stream>>>(partial, offs, row_start);
  scanC_kernel<<<SCAN_BLK, 256, 0, stream>>>(cursor, offs, row_start, dis);
  hipMemsetAsync(cursor, 0, (size_t)NN * 4, stream);
  scatter_kernel<<<2048, 256, 0, stream>>>(ei, flag, row_start, cursor, dis, csr_pack);

  const int gemm_blocks = (NN + 63) / 64;

  // ---- layer 0 (no residual: 128 -> 64) ----
  hipMemsetAsync(stats, 0, 128 * 4, stream);
  gemm_kernel<128><<<gemm_blocks, 256, 0, stream>>>(x0, W0, bufB);
  agg_kernel<<<2048, 256, 0, stream>>>(bufB, row_start, csr_pack, dis, bufC, stats);
  bnp_kernel<<<1, 64, 0, stream>>>(stats, g0, be0, bnp);
  apply_kernel<false><<<1024, 256, 0, stream>>>(bufC, bnp, nullptr, bufA);

  // ---- layer 1 (residual) ----
  hipMemsetAsync(stats, 0, 128 * 4, stream);
  gemm_kernel<64><<<gemm_blocks, 256, 0, stream>>>(bufA, W1, bufB);
  agg_kernel<<<2048, 256, 0, stream>>>(bufB, row_start, csr_pack, dis, bufC, stats);
  bnp_kernel<<<1, 64, 0, stream>>>(stats, g1, be1, bnp);
  apply_kernel<true><<<1024, 256, 0, stream>>>(bufC, bnp, bufA, out);

  // ---- layer 2 (residual) ----
  hipMemsetAsync(stats, 0, 128 * 4, stream);
  gemm_kernel<64><<<gemm_blocks, 256, 0, stream>>>(out, W2, bufB);
  agg_kernel<<<2048, 256, 0, stream>>>(bufB, row_start, csr_pack, dis, bufC, stats);
  bnp_kernel<<<1, 64, 0, stream>>>(stats, g2, be2, bnp);
  apply_kernel<true><<<1024, 256, 0, stream>>>(bufC, bnp, out, out);
}